// Round 10
// baseline (279.207 us; speedup 1.0000x reference)
//
#include <hip/hip_runtime.h>

#define N_PTS  (4*1024*1024)
#define NCLUST 65536

// ---------------------------------------------------------------------------
// Kernel 0: zero-fill pooled (ws is re-poisoned 0xAA before every launch).
// ---------------------------------------------------------------------------
__global__ __launch_bounds__(256) void k_zero(float4* __restrict__ p)
{
    p[(size_t)blockIdx.x * 256 + threadIdx.x] = make_float4(0.f, 0.f, 0.f, 0.f);
}

// ---------------------------------------------------------------------------
// Kernel 1: fc0 (3->64) + ReLU + sorted segment-max pool. (R7, unchanged)
// Wave = 64 lanes = 64 features; wave owns 256 points in 4 rounds of 64.
// Points staged into lanes (coalesced 12B/lane), broadcast via v_readlane
// (VALU pipe — not LDS, not K$). Run change -> ONE atomicMax instruction.
// ---------------------------------------------------------------------------
__global__ __launch_bounds__(256) void k_fc0_pool(
        const float* __restrict__ pts,          // [N,3]
        const int* __restrict__ clus,           // [N] sorted int32, < NCLUST
        const float* __restrict__ W0,           // [3,64]
        const float* __restrict__ b0,           // [64]
        float* __restrict__ pooled)             // [NCLUST,64], pre-zeroed
{
    const int tid  = threadIdx.x;
    const int lane = tid & 63;
    const int w    = tid >> 6;
    const int base = blockIdx.x * 1024 + w * 256;

    const float w0x = W0[lane];
    const float w0y = W0[64 + lane];
    const float w0z = W0[128 + lane];
    const float bb  = b0[lane];

    unsigned* pool_u = (unsigned*)pooled;
    int   cur  = clus[base];
    float vmax = 0.0f;

#define FLUSH(RID) { \
    atomicMax(&pool_u[(size_t)(RID) * 64 + lane], __float_as_uint(vmax)); \
    vmax = 0.0f; }

#define RL_F(v, i) __uint_as_float(__builtin_amdgcn_readlane(__float_as_uint(v), (i)))

    #pragma unroll 1
    for (int rnd = 0; rnd < 4; ++rnd) {
        const int rb = base + rnd * 64;
        const float* ps = pts + (size_t)rb * 3;
        const float vx = ps[lane * 3 + 0];
        const float vy = ps[lane * 3 + 1];
        const float vz = ps[lane * 3 + 2];
        const int   vc = clus[rb + lane];

        #pragma unroll
        for (int ch = 0; ch < 4; ++ch) {
            const int i0 = ch * 16;
            const int cf = __builtin_amdgcn_readlane(vc, i0);
            const int cl = __builtin_amdgcn_readlane(vc, i0 + 15);
            if (cf == cl) {
                if (cf != cur) { FLUSH(cur); cur = cf; }
                float m0 = vmax, m1 = vmax, m2 = vmax, m3 = vmax;
                #pragma unroll
                for (int t = 0; t < 16; t += 4) {
                    const float ax = RL_F(vx, i0 + t),     ay = RL_F(vy, i0 + t),     az = RL_F(vz, i0 + t);
                    const float bx = RL_F(vx, i0 + t + 1), by = RL_F(vy, i0 + t + 1), bz = RL_F(vz, i0 + t + 1);
                    const float cx = RL_F(vx, i0 + t + 2), cy = RL_F(vy, i0 + t + 2), cz = RL_F(vz, i0 + t + 2);
                    const float dx = RL_F(vx, i0 + t + 3), dy = RL_F(vy, i0 + t + 3), dz = RL_F(vz, i0 + t + 3);
                    m0 = fmaxf(m0, fmaf(ax, w0x, fmaf(ay, w0y, fmaf(az, w0z, bb))));
                    m1 = fmaxf(m1, fmaf(bx, w0x, fmaf(by, w0y, fmaf(bz, w0z, bb))));
                    m2 = fmaxf(m2, fmaf(cx, w0x, fmaf(cy, w0y, fmaf(cz, w0z, bb))));
                    m3 = fmaxf(m3, fmaf(dx, w0x, fmaf(dy, w0y, fmaf(dz, w0z, bb))));
                }
                vmax = fmaxf(fmaxf(m0, m1), fmaxf(m2, m3));
            } else {
                #pragma unroll 1
                for (int t = 0; t < 16; ++t) {
                    const int c = __builtin_amdgcn_readlane(vc, i0 + t);
                    if (c != cur) { FLUSH(cur); cur = c; }
                    const float sx = RL_F(vx, i0 + t);
                    const float sy = RL_F(vy, i0 + t);
                    const float sz = RL_F(vz, i0 + t);
                    vmax = fmaxf(vmax, fmaf(sx, w0x, fmaf(sy, w0y, fmaf(sz, w0z, bb))));
                }
            }
        }
    }
    FLUSH(cur);
#undef FLUSH
#undef RL_F
}

// ---------------------------------------------------------------------------
// Kernel 2 (v3): fused fc1+fc2 — ALL-REGISTER, 16 rows/wave, readlane
// h-broadcast. R9 post-mortem: per-wave rows=4 meant every wave read the
// whole W2 -> 2 GB L2 traffic (17.5 TB/s bound). Here each wave owns 16
// rows x all cols -> 512 MB total weight traffic, and h values are
// broadcast from lane registers via v_readlane (runtime-uniform SGPR
// index, register selection static -> loops stay ROLLED, ~2KB I-cache).
// Layout identity: phase A writes hA0[r]=h1[r][lane], hA1[r]=h1[r][lane+64]
// == exactly what phase B consumes. No LDS, no syncthreads, no shuffles.
// ---------------------------------------------------------------------------
__global__ __launch_bounds__(256, 4) void k_mlp(
        const float* __restrict__ pooled,
        const float* __restrict__ W1,
        const float* __restrict__ b1,
        const float* __restrict__ W2,
        const float* __restrict__ b2,
        float* __restrict__ out)
{
    const int tid  = threadIdx.x;
    const int lane = tid & 63;
    const int wv   = tid >> 6;
    const int r0   = (blockIdx.x * 4 + wv) * 16;   // wave's 16 cluster rows

#define RL_F(v, i) __uint_as_float(__builtin_amdgcn_readlane(__float_as_uint(v), (i)))

    // stage: pvr[r] in lane l = pooled[r0+r][l]  (coalesced 256B/row)
    float pvr[16];
    #pragma unroll
    for (int r = 0; r < 16; ++r)
        pvr[r] = pooled[(size_t)(r0 + r) * 64 + lane];

    // ---------------- Phase A: fc1 (64 -> 128) ----------------
    // hA0[r] = h1[r][lane], hA1[r] = h1[r][lane+64]
    const float bA0 = b1[lane];
    const float bA1 = b1[64 + lane];
    float hA0[16], hA1[16];
    #pragma unroll
    for (int r = 0; r < 16; ++r) { hA0[r] = bA0; hA1[r] = bA1; }

    #pragma unroll 2
    for (int k = 0; k < 64; ++k) {
        const float wa = W1[k * 128 + lane];        // coalesced, L2-hot
        const float wb = W1[k * 128 + 64 + lane];
        #pragma unroll
        for (int r = 0; r < 16; ++r) {
            const float h = RL_F(pvr[r], k);        // broadcast via VALU
            hA0[r] = fmaf(h, wa, hA0[r]);
            hA1[r] = fmaf(h, wb, hA1[r]);
        }
    }
    #pragma unroll
    for (int r = 0; r < 16; ++r) {
        hA0[r] = fmaxf(hA0[r], 0.0f);
        hA1[r] = fmaxf(hA1[r], 0.0f);
    }

    // ---------------- Phase B: fc2 (128 -> 256) ----------------
    // lane owns out cols lane*4..+3; acc[r][0..3] as 4 named arrays
    const float4 bv = ((const float4*)b2)[lane];
    float a0[16], a1[16], a2[16], a3[16];
    #pragma unroll
    for (int r = 0; r < 16; ++r) { a0[r] = bv.x; a1[r] = bv.y; a2[r] = bv.z; a3[r] = bv.w; }

    #pragma unroll 2
    for (int k = 0; k < 64; ++k) {                  // k-half 0: h from hA0
        const float4 wv4 = *(const float4*)(W2 + (size_t)k * 256 + lane * 4);
        #pragma unroll
        for (int r = 0; r < 16; ++r) {
            const float h = RL_F(hA0[r], k);
            a0[r] = fmaf(h, wv4.x, a0[r]);
            a1[r] = fmaf(h, wv4.y, a1[r]);
            a2[r] = fmaf(h, wv4.z, a2[r]);
            a3[r] = fmaf(h, wv4.w, a3[r]);
        }
    }
    #pragma unroll 2
    for (int k = 0; k < 64; ++k) {                  // k-half 1: h from hA1
        const float4 wv4 = *(const float4*)(W2 + (size_t)(64 + k) * 256 + lane * 4);
        #pragma unroll
        for (int r = 0; r < 16; ++r) {
            const float h = RL_F(hA1[r], k);
            a0[r] = fmaf(h, wv4.x, a0[r]);
            a1[r] = fmaf(h, wv4.y, a1[r]);
            a2[r] = fmaf(h, wv4.z, a2[r]);
            a3[r] = fmaf(h, wv4.w, a3[r]);
        }
    }

    // store: wave writes 16 contiguous 1KB rows
    #pragma unroll
    for (int r = 0; r < 16; ++r) {
        float4 o;
        o.x = fmaxf(a0[r], 0.0f);
        o.y = fmaxf(a1[r], 0.0f);
        o.z = fmaxf(a2[r], 0.0f);
        o.w = fmaxf(a3[r], 0.0f);
        *(float4*)(out + (size_t)(r0 + r) * 256 + lane * 4) = o;
    }
#undef RL_F
}

// ---------------------------------------------------------------------------
extern "C" void kernel_launch(void* const* d_in, const int* in_sizes, int n_in,
                              void* d_out, int out_size, void* d_ws, size_t ws_size,
                              hipStream_t stream) {
    const float* points  = (const float*)d_in[0];
    const int*   cluster = (const int*)d_in[1];   // int32 on device (harness)
    const float* W0      = (const float*)d_in[2];
    const float* b0      = (const float*)d_in[3];
    const float* W1      = (const float*)d_in[4];
    const float* b1      = (const float*)d_in[5];
    const float* W2      = (const float*)d_in[6];
    const float* b2      = (const float*)d_in[7];
    float* out = (float*)d_out;

    float* pooled = (float*)d_ws;   // 16 MB

    k_zero<<<(NCLUST * 64 / 4) / 256, 256, 0, stream>>>((float4*)pooled);
    k_fc0_pool<<<N_PTS / 1024, 256, 0, stream>>>(points, cluster, W0, b0, pooled);
    k_mlp<<<NCLUST / 64, 256, 0, stream>>>(pooled, W1, b1, W2, b2, out);
}

// Round 11
// 206.121 us; speedup vs baseline: 1.3546x; 1.3546x over previous
//
#include <hip/hip_runtime.h>

#define N_PTS  (4*1024*1024)
#define NCLUST 65536

typedef short bf16x8 __attribute__((ext_vector_type(8)));
typedef float f32x4  __attribute__((ext_vector_type(4)));

__device__ __forceinline__ unsigned short f2bf(float x) {
    unsigned u = __float_as_uint(x);
    u = (u + 0x7FFFu + ((u >> 16) & 1u)) >> 16;   // RNE
    return (unsigned short)u;
}
__device__ __forceinline__ float bf2f(unsigned short h) {
    return __uint_as_float(((unsigned)h) << 16);
}

// ---------------------------------------------------------------------------
// Kernel 0: zero-fill pooled (ws is re-poisoned 0xAA before every launch).
// ---------------------------------------------------------------------------
__global__ __launch_bounds__(256) void k_zero(float4* __restrict__ p)
{
    p[(size_t)blockIdx.x * 256 + threadIdx.x] = make_float4(0.f, 0.f, 0.f, 0.f);
}

// ---------------------------------------------------------------------------
// Kernel P: transpose W1,W2 and split into bf16 hi/lo (k-contiguous rows so
// MFMA B-fragments are single 16B loads). Split-bf16: x ~= hi + lo with
// |x - hi - lo| ~ 2^-17 |x|  ->  3-pass MFMA keeps fp32-level accuracy.
// ---------------------------------------------------------------------------
__global__ __launch_bounds__(256) void k_prep(
        const float* __restrict__ W1, const float* __restrict__ W2,
        unsigned short* __restrict__ W1Th, unsigned short* __restrict__ W1Tl,
        unsigned short* __restrict__ W2Th, unsigned short* __restrict__ W2Tl)
{
    const int i = blockIdx.x * 256 + threadIdx.x;
    if (i < 8192) {                 // W1T[n][k] = W1[k][n], n<128, k<64
        const int n = i >> 6, k = i & 63;
        const float x = W1[k * 128 + n];
        const unsigned short h = f2bf(x);
        W1Th[i] = h; W1Tl[i] = f2bf(x - bf2f(h));
    }
    const int j = i - 8192;
    if (j >= 0 && j < 32768) {      // W2T[n][k] = W2[k][n], n<256, k<128
        const int n = j >> 7, k = j & 127;
        const float x = W2[k * 256 + n];
        const unsigned short h = f2bf(x);
        W2Th[j] = h; W2Tl[j] = f2bf(x - bf2f(h));
    }
}

// ---------------------------------------------------------------------------
// Kernel 1: fc0 (3->64) + ReLU + sorted segment-max pool. (R7, unchanged)
// Points staged into lanes, broadcast via v_readlane (VALU pipe).
// ---------------------------------------------------------------------------
__global__ __launch_bounds__(256) void k_fc0_pool(
        const float* __restrict__ pts,
        const int* __restrict__ clus,
        const float* __restrict__ W0,
        const float* __restrict__ b0,
        float* __restrict__ pooled)
{
    const int tid  = threadIdx.x;
    const int lane = tid & 63;
    const int w    = tid >> 6;
    const int base = blockIdx.x * 1024 + w * 256;

    const float w0x = W0[lane];
    const float w0y = W0[64 + lane];
    const float w0z = W0[128 + lane];
    const float bb  = b0[lane];

    unsigned* pool_u = (unsigned*)pooled;
    int   cur  = clus[base];
    float vmax = 0.0f;

#define FLUSH(RID) { \
    atomicMax(&pool_u[(size_t)(RID) * 64 + lane], __float_as_uint(vmax)); \
    vmax = 0.0f; }

#define RL_F(v, i) __uint_as_float(__builtin_amdgcn_readlane(__float_as_uint(v), (i)))

    #pragma unroll 1
    for (int rnd = 0; rnd < 4; ++rnd) {
        const int rb = base + rnd * 64;
        const float* ps = pts + (size_t)rb * 3;
        const float vx = ps[lane * 3 + 0];
        const float vy = ps[lane * 3 + 1];
        const float vz = ps[lane * 3 + 2];
        const int   vc = clus[rb + lane];

        #pragma unroll
        for (int ch = 0; ch < 4; ++ch) {
            const int i0 = ch * 16;
            const int cf = __builtin_amdgcn_readlane(vc, i0);
            const int cl = __builtin_amdgcn_readlane(vc, i0 + 15);
            if (cf == cl) {
                if (cf != cur) { FLUSH(cur); cur = cf; }
                float m0 = vmax, m1 = vmax, m2 = vmax, m3 = vmax;
                #pragma unroll
                for (int t = 0; t < 16; t += 4) {
                    const float ax = RL_F(vx, i0 + t),     ay = RL_F(vy, i0 + t),     az = RL_F(vz, i0 + t);
                    const float bx = RL_F(vx, i0 + t + 1), by = RL_F(vy, i0 + t + 1), bz = RL_F(vz, i0 + t + 1);
                    const float cx = RL_F(vx, i0 + t + 2), cy = RL_F(vy, i0 + t + 2), cz = RL_F(vz, i0 + t + 2);
                    const float dx = RL_F(vx, i0 + t + 3), dy = RL_F(vy, i0 + t + 3), dz = RL_F(vz, i0 + t + 3);
                    m0 = fmaxf(m0, fmaf(ax, w0x, fmaf(ay, w0y, fmaf(az, w0z, bb))));
                    m1 = fmaxf(m1, fmaf(bx, w0x, fmaf(by, w0y, fmaf(bz, w0z, bb))));
                    m2 = fmaxf(m2, fmaf(cx, w0x, fmaf(cy, w0y, fmaf(cz, w0z, bb))));
                    m3 = fmaxf(m3, fmaf(dx, w0x, fmaf(dy, w0y, fmaf(dz, w0z, bb))));
                }
                vmax = fmaxf(fmaxf(m0, m1), fmaxf(m2, m3));
            } else {
                #pragma unroll 1
                for (int t = 0; t < 16; ++t) {
                    const int c = __builtin_amdgcn_readlane(vc, i0 + t);
                    if (c != cur) { FLUSH(cur); cur = c; }
                    const float sx = RL_F(vx, i0 + t);
                    const float sy = RL_F(vy, i0 + t);
                    const float sz = RL_F(vz, i0 + t);
                    vmax = fmaxf(vmax, fmaf(sx, w0x, fmaf(sy, w0y, fmaf(sz, w0z, bb))));
                }
            }
        }
    }
    FLUSH(cur);
#undef FLUSH
#undef RL_F
}

// ---------------------------------------------------------------------------
// Kernel 2 (v4): fused fc1+fc2 via MFMA 16x16x32 bf16, SPLIT-BF16 3-pass
// (hi*hi + hi*lo + lo*hi -> ~2^-17 relative error, fp32-level).
// R10 post-mortem: fp32 VALU floor ~90us for 5.4 GFLOP; MFMA compute is
// ~1.2K cyc/wave -> staging-dominated. Block = 4 waves / 64 rows.
// Fragment layouts (guide §3, m89-verified C/D):
//   A: row=lane&15, k=(lane>>4)*8+e (8 bf16 = one 16B load, LDS)
//   B: col=lane&15, k=(lane>>4)*8+e (16B load from pre-transposed W)
//   C/D: col=lane&15, row=(lane>>4)*4+i
// LDS pads: A [64][72] (stride 144B -> 2-way banks, free, 16B-aligned);
//           H [64][136] (stride 272B -> 2-way, 16B-aligned). Total 53.2 KB.
// ---------------------------------------------------------------------------
__global__ __launch_bounds__(256, 3) void k_mlp(
        const float* __restrict__ pooled,
        const unsigned short* __restrict__ W1Th, const unsigned short* __restrict__ W1Tl,
        const unsigned short* __restrict__ W2Th, const unsigned short* __restrict__ W2Tl,
        const float* __restrict__ b1, const float* __restrict__ b2,
        float* __restrict__ out)
{
    __shared__ unsigned short Ah[64 * 72], Al[64 * 72];
    __shared__ unsigned short Hh[64 * 136], Hl[64 * 136];

    const int tid  = threadIdx.x;
    const int lane = tid & 63;
    const int w    = tid >> 6;      // wave 0..3
    const int r0   = blockIdx.x * 64;
    const int lr   = lane & 15;     // fragment row/col
    const int lg   = lane >> 4;     // k-group / row-group

    // ---- stage P[64][64] -> bf16 hi/lo in LDS ----
    #pragma unroll
    for (int j = 0; j < 16; ++j) {
        const int idx = j * 256 + tid;            // 0..4095
        const int row = idx >> 6, col = idx & 63;
        const float x = pooled[(size_t)(r0 + row) * 64 + col];
        const unsigned short h = f2bf(x);
        Ah[row * 72 + col] = h;
        Al[row * 72 + col] = f2bf(x - bf2f(h));
    }
    __syncthreads();

    // ---- fc1: [64x64] @ [64x128] + b1, ReLU -> H ----
    {
        const float bias0 = b1[w * 32 + lr];
        const float bias1 = b1[w * 32 + 16 + lr];
        f32x4 acc[4][2];
        #pragma unroll
        for (int m = 0; m < 4; ++m) {
            acc[m][0] = (f32x4){bias0, bias0, bias0, bias0};
            acc[m][1] = (f32x4){bias1, bias1, bias1, bias1};
        }
        #pragma unroll
        for (int s = 0; s < 2; ++s) {
            const int k  = s * 32 + lg * 8;
            const int c0 = (w * 32 + lr) * 64 + k;
            const int c1 = c0 + 16 * 64;
            const bf16x8 b0h = *(const bf16x8*)(W1Th + c0);
            const bf16x8 b0l = *(const bf16x8*)(W1Tl + c0);
            const bf16x8 b1h_ = *(const bf16x8*)(W1Th + c1);
            const bf16x8 b1l_ = *(const bf16x8*)(W1Tl + c1);
            #pragma unroll
            for (int m = 0; m < 4; ++m) {
                const int ao = (m * 16 + lr) * 72 + k;
                const bf16x8 ah = *(const bf16x8*)(Ah + ao);
                const bf16x8 al = *(const bf16x8*)(Al + ao);
                acc[m][0] = __builtin_amdgcn_mfma_f32_16x16x32_bf16(ah, b0h, acc[m][0], 0, 0, 0);
                acc[m][0] = __builtin_amdgcn_mfma_f32_16x16x32_bf16(ah, b0l, acc[m][0], 0, 0, 0);
                acc[m][0] = __builtin_amdgcn_mfma_f32_16x16x32_bf16(al, b0h, acc[m][0], 0, 0, 0);
                acc[m][1] = __builtin_amdgcn_mfma_f32_16x16x32_bf16(ah, b1h_, acc[m][1], 0, 0, 0);
                acc[m][1] = __builtin_amdgcn_mfma_f32_16x16x32_bf16(ah, b1l_, acc[m][1], 0, 0, 0);
                acc[m][1] = __builtin_amdgcn_mfma_f32_16x16x32_bf16(al, b1h_, acc[m][1], 0, 0, 0);
            }
        }
        // ReLU + re-split -> H (bf16 hi/lo)
        #pragma unroll
        for (int m = 0; m < 4; ++m)
          #pragma unroll
          for (int n = 0; n < 2; ++n)
            #pragma unroll
            for (int i = 0; i < 4; ++i) {
                const int row = m * 16 + lg * 4 + i;
                const int col = w * 32 + n * 16 + lr;
                const float v = fmaxf(acc[m][n][i], 0.0f);
                const unsigned short h = f2bf(v);
                Hh[row * 136 + col] = h;
                Hl[row * 136 + col] = f2bf(v - bf2f(h));
            }
    }
    __syncthreads();

    // ---- fc2: [64x128] @ [128x256] + b2, ReLU -> out ----
    {
        f32x4 acc[4][4];
        #pragma unroll
        for (int n = 0; n < 4; ++n) {
            const float bb = b2[w * 64 + n * 16 + lr];
            #pragma unroll
            for (int m = 0; m < 4; ++m) acc[m][n] = (f32x4){bb, bb, bb, bb};
        }
        #pragma unroll
        for (int s = 0; s < 4; ++s) {
            const int k = s * 32 + lg * 8;
            bf16x8 bh[4], bl[4];
            #pragma unroll
            for (int n = 0; n < 4; ++n) {
                const int c = (w * 64 + n * 16 + lr) * 128 + k;
                bh[n] = *(const bf16x8*)(W2Th + c);
                bl[n] = *(const bf16x8*)(W2Tl + c);
            }
            #pragma unroll
            for (int m = 0; m < 4; ++m) {
                const int ao = (m * 16 + lr) * 136 + k;
                const bf16x8 ah = *(const bf16x8*)(Hh + ao);
                const bf16x8 al = *(const bf16x8*)(Hl + ao);
                #pragma unroll
                for (int n = 0; n < 4; ++n) {
                    acc[m][n] = __builtin_amdgcn_mfma_f32_16x16x32_bf16(ah, bh[n], acc[m][n], 0, 0, 0);
                    acc[m][n] = __builtin_amdgcn_mfma_f32_16x16x32_bf16(ah, bl[n], acc[m][n], 0, 0, 0);
                    acc[m][n] = __builtin_amdgcn_mfma_f32_16x16x32_bf16(al, bh[n], acc[m][n], 0, 0, 0);
                }
            }
        }
        #pragma unroll
        for (int m = 0; m < 4; ++m)
          #pragma unroll
          for (int n = 0; n < 4; ++n)
            #pragma unroll
            for (int i = 0; i < 4; ++i) {
                const int row = r0 + m * 16 + lg * 4 + i;
                const int col = w * 64 + n * 16 + lr;
                out[(size_t)row * 256 + col] = fmaxf(acc[m][n][i], 0.0f);
            }
    }
}

// ---------------------------------------------------------------------------
extern "C" void kernel_launch(void* const* d_in, const int* in_sizes, int n_in,
                              void* d_out, int out_size, void* d_ws, size_t ws_size,
                              hipStream_t stream) {
    const float* points  = (const float*)d_in[0];
    const int*   cluster = (const int*)d_in[1];   // int32 on device (harness)
    const float* W0      = (const float*)d_in[2];
    const float* b0      = (const float*)d_in[3];
    const float* W1      = (const float*)d_in[4];
    const float* b1      = (const float*)d_in[5];
    const float* W2      = (const float*)d_in[6];
    const float* b2      = (const float*)d_in[7];
    float* out = (float*)d_out;

    char* base = (char*)d_ws;
    float* pooled = (float*)base;                                    // 16 MB
    unsigned short* W1Th = (unsigned short*)(base + (16u << 20));
    unsigned short* W1Tl = W1Th + 8192;
    unsigned short* W2Th = W1Tl + 8192;
    unsigned short* W2Tl = W2Th + 32768;

    k_zero<<<(NCLUST * 64 / 4) / 256, 256, 0, stream>>>((float4*)pooled);
    k_prep<<<160, 256, 0, stream>>>(W1, W2, W1Th, W1Tl, W2Th, W2Tl);
    k_fc0_pool<<<N_PTS / 1024, 256, 0, stream>>>(points, cluster, W0, b0, pooled);
    k_mlp<<<NCLUST / 64, 256, 0, stream>>>(pooled, W1Th, W1Tl, W2Th, W2Tl, b1, b2, out);
}